// Round 4
// baseline (366.536 us; speedup 1.0000x reference)
//
#include <hip/hip_runtime.h>

// SelfAttention: x(4,2048,1024) fp32; Linear y = x @ W^T + b for Q,K,V;
// S = QK^T/32; P = softmax(S); O = P V; out = O @ Wo^T + bo.
// bf16 MFMA (16x16x32) m97-style gemm_bt with XOR-swizzled LDS (R2: 0 conflicts).
// R3: fused Q+K proj, VT = gemm(Wv, x) directly, bf16 S, in-place softmax.
// R4: pad all 2048-wide buffers to ld=2080 elems (4160B row stride) to break
//     the 4KB pow-2 stride aliasing that cost ~12% on every R3 GEMM
//     (R3: QK/S GEMMs 518 TF vs R2's 592 TF, same FETCH bytes).
// Workspace (~106 MB):
//   [0,16M)        xb bf16 [8192][1024]  -> later O (attn out, bf16)
//   [16M,20M)      wqkb bf16 [2048][1024] (wq rows 0-1023, wk 1024-2047)
//   [20M,22M)      wvb    [22M,24M) wob
//   [24M,+34.1M)   QK bf16 [8192][2080] (cols 0-1023 Q, 1024-2047 K, 2048+ pad)
//   then           VT bf16 [4][1024][2080]
//   then           S  bf16 [4][2048][2080] -> softmax in place -> P
//   then           bqk fp32 [2048]

#define LDP 2080  // padded leading dim for 2048-wide buffers

typedef __bf16 bf16x8 __attribute__((ext_vector_type(8)));
typedef float f32x4 __attribute__((ext_vector_type(4)));
typedef unsigned short ushort8 __attribute__((ext_vector_type(8)));

__device__ __forceinline__ unsigned short f32_to_bf16(float f) {
  unsigned int u = __float_as_uint(f);
  u += 0x7fffu + ((u >> 16) & 1u);   // round-to-nearest-even
  return (unsigned short)(u >> 16);
}

__device__ __forceinline__ float bf16_to_f32(unsigned short u) {
  return __uint_as_float((unsigned int)u << 16);
}

__device__ __forceinline__ void load_lds16(const void* g, void* l) {
  __builtin_amdgcn_global_load_lds(
      (const __attribute__((address_space(1))) void*)g,
      (__attribute__((address_space(3))) void*)l, 16, 0, 0);
}

// ------------------------------------------------------------- cast kernels
__global__ __launch_bounds__(256) void cast_f32_bf16(
    const float4* __restrict__ in, ushort4* __restrict__ out, int n4) {
  int i = blockIdx.x * 256 + threadIdx.x;
  if (i < n4) {
    float4 f = in[i];
    ushort4 u;
    u.x = f32_to_bf16(f.x);
    u.y = f32_to_bf16(f.y);
    u.z = f32_to_bf16(f.z);
    u.w = f32_to_bf16(f.w);
    out[i] = u;
  }
}

// all 4 weight matrices in one launch; wq,wk go into concat wqkb
__global__ __launch_bounds__(256) void cast_weights(
    const float4* __restrict__ wq, const float4* __restrict__ wk,
    const float4* __restrict__ wv, const float4* __restrict__ wo,
    ushort4* __restrict__ wqkb, ushort4* __restrict__ wvb,
    ushort4* __restrict__ wob) {
  const int b = blockIdx.x;
  const int seg = b >> 10;                          // 0..3
  const int idx = ((b & 1023) << 8) + threadIdx.x;  // 0..262143 float4s
  const float4* src = seg == 0 ? wq : seg == 1 ? wk : seg == 2 ? wv : wo;
  ushort4* dst = seg == 0 ? wqkb
               : seg == 1 ? (wqkb + 262144)
               : seg == 2 ? wvb : wob;
  float4 f = src[idx];
  ushort4 u;
  u.x = f32_to_bf16(f.x);
  u.y = f32_to_bf16(f.y);
  u.z = f32_to_bf16(f.z);
  u.w = f32_to_bf16(f.w);
  dst[idx] = u;
}

__global__ __launch_bounds__(256) void concat_bias(
    const float* __restrict__ bq, const float* __restrict__ bk,
    float* __restrict__ bqk) {
  int i = blockIdx.x * 256 + threadIdx.x;  // grid 8 -> 2048
  bqk[i] = (i < 1024) ? bq[i] : bk[i - 1024];
}

// ------------------------------------------------------------ gemm (B^T form)
// C[b][M][N] = alpha * A[b][M][K] * B[b][N][K]^T + bias
// bias_mode: 0 none, 1 per-col (bias[N]), 2 per-row (bias[M]).
// Tile 128x128, BK=64, 4 waves 2x2, 4x4 16x16x32 MFMA acc per wave.
// LDS: physical 16B chunk p of row r holds logical chunk p^(r&7) (no conflicts).
__global__ __launch_bounds__(256) void gemm_bt(
    const unsigned short* __restrict__ A, const unsigned short* __restrict__ B,
    void* __restrict__ C, const float* __restrict__ bias,
    int M, int N, int K, int ldA, int ldB, int ldC,
    float alpha, int out_bf16, int bias_mode,
    long long sA, long long sB, long long sC) {
  __shared__ unsigned short As[128 * 64];
  __shared__ unsigned short Bs[128 * 64];

  const int bz = blockIdx.z;
  A += (long long)bz * sA;
  B += (long long)bz * sB;

  const int bm = blockIdx.y, bn = blockIdx.x;
  const int tid = threadIdx.x;
  const int lane = tid & 63, wave = tid >> 6;
  const int wr = wave >> 1, wc = wave & 1;
  const int l16 = lane & 15, quad = lane >> 4;

  f32x4 acc[4][4] = {};

  // staging: thread t covers row (t>>3)+32r; LDS physical chunk (t&7) gets
  // logical chunk (t&7)^(row&7).
  const int srow = tid >> 3;
  const int xr = srow & 7;
  const int scol = ((tid & 7) ^ xr) * 8;
  const unsigned short* gA = A + (long long)(bm * 128 + srow) * ldA + scol;
  const unsigned short* gB = B + (long long)(bn * 128 + srow) * ldB + scol;
  char* ldsA = (char*)As + wave * 1024;  // wave-uniform base; HW adds lane*16
  char* ldsB = (char*)Bs + wave * 1024;

  for (int k0 = 0; k0 < K; k0 += 64) {
#pragma unroll
    for (int r = 0; r < 4; r++)
      load_lds16(gA + k0 + (long long)r * 32 * ldA, ldsA + r * 4096);
#pragma unroll
    for (int r = 0; r < 4; r++)
      load_lds16(gB + k0 + (long long)r * 32 * ldB, ldsB + r * 4096);
    __syncthreads();  // drains vmcnt: LDS tiles ready

    const int swz = l16 & 7;
#pragma unroll
    for (int kk = 0; kk < 64; kk += 32) {
      bf16x8 af[4], bf[4];
      const int lc = (kk >> 3) + quad;   // logical chunk 0..7
      const int pco = (lc ^ swz) * 8;    // physical chunk offset, elems
#pragma unroll
      for (int mi = 0; mi < 4; mi++)
        af[mi] = *(const bf16x8*)(As + (wr * 64 + mi * 16 + l16) * 64 + pco);
#pragma unroll
      for (int ni = 0; ni < 4; ni++)
        bf[ni] = *(const bf16x8*)(Bs + (wc * 64 + ni * 16 + l16) * 64 + pco);
#pragma unroll
      for (int mi = 0; mi < 4; mi++)
#pragma unroll
        for (int ni = 0; ni < 4; ni++)
          acc[mi][ni] = __builtin_amdgcn_mfma_f32_16x16x32_bf16(
              af[mi], bf[ni], acc[mi][ni], 0, 0, 0);
    }
    __syncthreads();  // protect LDS before next stage overwrites
  }

  // epilogue: D element (row = quad*4+reg, col = l16) per 16x16 tile
  const int orow0 = bm * 128 + wr * 64 + quad * 4;
  const int ocol0 = bn * 128 + wc * 64 + l16;
  if (out_bf16) {
    unsigned short* Cp = (unsigned short*)C + (long long)bz * sC;
#pragma unroll
    for (int mi = 0; mi < 4; mi++)
#pragma unroll
      for (int ni = 0; ni < 4; ni++) {
        const int col = ocol0 + ni * 16;
        const float cb = (bias_mode == 1) ? bias[col] : 0.f;
#pragma unroll
        for (int r = 0; r < 4; r++) {
          const int row = orow0 + mi * 16 + r;
          const float bv = (bias_mode == 2) ? bias[row] : cb;
          const float o = acc[mi][ni][r] * alpha + bv;
          Cp[(long long)row * ldC + col] = f32_to_bf16(o);
        }
      }
  } else {
    float* Cp = (float*)C + (long long)bz * sC;
#pragma unroll
    for (int mi = 0; mi < 4; mi++)
#pragma unroll
      for (int ni = 0; ni < 4; ni++) {
        const int col = ocol0 + ni * 16;
        const float cb = (bias_mode == 1) ? bias[col] : 0.f;
#pragma unroll
        for (int r = 0; r < 4; r++) {
          const int row = orow0 + mi * 16 + r;
          const float bv = (bias_mode == 2) ? bias[row] : cb;
          const float o = acc[mi][ni][r] * alpha + bv;
          Cp[(long long)row * ldC + col] = o;
        }
      }
  }
}

// ------------------------------------------------------- row softmax, bf16
// S: [8192][LDP] bf16 (2048 valid cols), in place. One block per row.
__global__ __launch_bounds__(256) void softmax_rows_bf16(
    unsigned short* __restrict__ S) {
  const long long row = blockIdx.x;
  unsigned short* s = S + row * LDP;
  const int t = threadIdx.x;
  ushort8 u = *(const ushort8*)(s + t * 8);
  float v[8];
  float mx = -3.4e38f;
#pragma unroll
  for (int i = 0; i < 8; i++) {
    v[i] = bf16_to_f32(u[i]);
    mx = fmaxf(mx, v[i]);
  }
#pragma unroll
  for (int o = 32; o >= 1; o >>= 1) mx = fmaxf(mx, __shfl_xor(mx, o));
  __shared__ float red[4], red2[4];
  if ((t & 63) == 0) red[t >> 6] = mx;
  __syncthreads();
  mx = fmaxf(fmaxf(red[0], red[1]), fmaxf(red[2], red[3]));
  float sum = 0.f;
#pragma unroll
  for (int i = 0; i < 8; i++) {
    v[i] = __expf(v[i] - mx);
    sum += v[i];
  }
#pragma unroll
  for (int o = 32; o >= 1; o >>= 1) sum += __shfl_xor(sum, o);
  if ((t & 63) == 0) red2[t >> 6] = sum;
  __syncthreads();
  sum = red2[0] + red2[1] + red2[2] + red2[3];
  const float inv = 1.0f / sum;
  ushort8 w;
#pragma unroll
  for (int i = 0; i < 8; i++) w[i] = f32_to_bf16(v[i] * inv);
  *(ushort8*)(s + t * 8) = w;
}

// ----------------------------------------------------------------- launcher
extern "C" void kernel_launch(void* const* d_in, const int* in_sizes, int n_in,
                              void* d_out, int out_size, void* d_ws,
                              size_t ws_size, hipStream_t stream) {
  const float* x = (const float*)d_in[0];
  const float* wq = (const float*)d_in[1];
  const float* bq = (const float*)d_in[2];
  const float* wk = (const float*)d_in[3];
  const float* bk = (const float*)d_in[4];
  const float* wv = (const float*)d_in[5];
  const float* bv = (const float*)d_in[6];
  const float* wo = (const float*)d_in[7];
  const float* bo = (const float*)d_in[8];
  float* out = (float*)d_out;
  char* ws = (char*)d_ws;

  const size_t OFF_XB  = 0;                              // 16 MB
  const size_t OFF_WQK = 16777216;                       // 4 MB
  const size_t OFF_WV  = 20971520;                       // 2 MB
  const size_t OFF_WO  = 23068672;                       // 2 MB
  const size_t OFF_QK  = 25165824;                       // 8192*LDP*2
  const size_t OFF_VT  = OFF_QK + 8192ull * LDP * 2;     // 4*1024*LDP*2
  const size_t OFF_S   = OFF_VT + 4096ull * LDP * 2;     // 4*2048*LDP*2
  const size_t OFF_BQK = OFF_S + 8192ull * LDP * 2;      // 8 KB

  unsigned short* xb   = (unsigned short*)(ws + OFF_XB);   // later O
  unsigned short* wqkb = (unsigned short*)(ws + OFF_WQK);
  unsigned short* wvb  = (unsigned short*)(ws + OFF_WV);
  unsigned short* wob  = (unsigned short*)(ws + OFF_WO);
  unsigned short* QK   = (unsigned short*)(ws + OFF_QK);   // [8192][LDP]
  unsigned short* VT   = (unsigned short*)(ws + OFF_VT);   // [4][1024][LDP]
  unsigned short* S    = (unsigned short*)(ws + OFF_S);    // [4][2048][LDP]
  float*          bqk  = (float*)(ws + OFF_BQK);
  unsigned short* O    = xb;

  // 1) casts
  cast_f32_bf16<<<dim3(8192), dim3(256), 0, stream>>>((const float4*)x,
                                                      (ushort4*)xb, 2097152);
  cast_weights<<<dim3(4096), dim3(256), 0, stream>>>(
      (const float4*)wq, (const float4*)wk, (const float4*)wv,
      (const float4*)wo, (ushort4*)wqkb, (ushort4*)wvb, (ushort4*)wob);
  concat_bias<<<dim3(8), dim3(256), 0, stream>>>(bq, bk, bqk);

  // 2) fused Q+K projection: QK[8192][2048 of LDP] = xb @ wqkb^T + bqk (bf16)
  gemm_bt<<<dim3(16, 64, 1), dim3(256), 0, stream>>>(
      xb, wqkb, QK, bqk, 8192, 2048, 1024, 1024, 1024, LDP, 1.f, 1, 1, 0, 0,
      0);

  // 3) VT[b][d][s] = sum_k wv[d][k] x[b][s][k] + bv[d]  (per-row bias)
  gemm_bt<<<dim3(16, 8, 4), dim3(256), 0, stream>>>(
      wvb, xb, VT, bv, 1024, 2048, 1024, 1024, 1024, LDP, 1.f, 1, 2, 0,
      2048ll * 1024, 1024ll * LDP);

  // 4) S = Q K^T / 32 (bf16 out, fp32 accum), batched over 4
  gemm_bt<<<dim3(16, 16, 4), dim3(256), 0, stream>>>(
      QK, QK + 1024, S, nullptr, 2048, 2048, 1024, LDP, LDP, LDP, 0.03125f, 1,
      0, 2048ll * LDP, 2048ll * LDP, 2048ll * LDP);

  // 5) P = softmax rows of S, in place
  softmax_rows_bf16<<<dim3(8192), dim3(256), 0, stream>>>(S);

  // 6) O = P @ V (B = VT in B^T form), bf16, over xb
  gemm_bt<<<dim3(8, 16, 4), dim3(256), 0, stream>>>(
      S, VT, O, nullptr, 2048, 1024, 2048, LDP, LDP, 1024, 1.f, 1, 0,
      2048ll * LDP, 1024ll * LDP, 2048ll * 1024);

  // 7) out = O @ Wo^T + bo, fp32 to d_out
  gemm_bt<<<dim3(8, 64, 1), dim3(256), 0, stream>>>(
      O, wob, out, bo, 8192, 1024, 1024, 1024, 1024, 1024, 1.f, 0, 1, 0, 0, 0);
}